// Round 8
// baseline (168.835 us; speedup 1.0000x reference)
//
#include <hip/hip_runtime.h>

#define N_NODES 50000
#define N_EDGES 800000
#define CH 128
#define NBUCK 196          // ceil(50000/256): buckets of 256 dst nodes
#define B_BIN 250          // bin-pass blocks
#define CHUNK 3200         // edges per bin-pass block (250*3200 = 800000)
#define G_GEMM 782         // ceil(50000/64)

typedef __attribute__((ext_vector_type(8))) short bf16x8;
typedef __attribute__((ext_vector_type(4))) float f32x4;

__device__ __forceinline__ float bf2f(unsigned short u) {
    union { unsigned int i; float f; } c;
    c.i = ((unsigned int)u) << 16;
    return c.f;
}
__device__ __forceinline__ unsigned short f2bf(float f) {
    union { float f; unsigned int i; } c;
    c.f = f;
    unsigned int lsb = (c.i >> 16) & 1u;
    c.i += 0x7fffu + lsb;          // round-to-nearest-even
    return (unsigned short)(c.i >> 16);
}

// ---------------- W transpose to bf16: Wt[n][k] = bf16(W[k][n]); 2 blocks ----------------
__global__ __launch_bounds__(256) void k_wt(const float* __restrict__ Wa,
                                            const float* __restrict__ Wb,
                                            unsigned short* __restrict__ Wta,
                                            unsigned short* __restrict__ Wtb) {
    const float* W = blockIdx.x ? Wb : Wa;
    unsigned short* Wt = blockIdx.x ? Wtb : Wta;
    const int tid = threadIdx.x;
    for (int i = 0; i < 64; ++i) {
        int idx = i * 256 + tid;           // n*128 + k
        int n = idx >> 7, kk = idx & 127;
        Wt[idx] = f2bf(W[kk * CH + n]);
    }
}

// ---------------- mega: blocks [0,B_BIN) = bucket histogram; rest = GEMM1 (unscaled) ----------------
// GEMM1: HS1u = bf16(X @ W1). X read f32, converted inline. 4 waves/block, 16 rows/wave.
// C/D layout (HW-verified): col = l&15, row = (l>>4)*4 + reg.
__global__ __launch_bounds__(256) void k_mega(
        const int* __restrict__ ei, int* __restrict__ blk_base,
        const float* __restrict__ X, const unsigned short* __restrict__ Wt1,
        unsigned short* __restrict__ HS1u) {
    const int tid = threadIdx.x;
    const int b = blockIdx.x;

    if (b < B_BIN) {       // ---- bucket histogram ----
        __shared__ int h[NBUCK];
        for (int i = tid; i < NBUCK; i += 256) h[i] = 0;
        __syncthreads();
        const int e0 = b * CHUNK;
        const int* dst = ei + N_EDGES;
        for (int i = tid; i < CHUNK; i += 256)
            atomicAdd(&h[dst[e0 + i] >> 8], 1);
        __syncthreads();
        for (int k = tid; k < NBUCK; k += 256)
            blk_base[b * NBUCK + k] = h[k];
        return;
    }

    // ---- GEMM1 ----
    const int gb = b - B_BIN;
    const int l = tid & 63, w = tid >> 6;
    const int lm = l & 15, lk = l >> 4;
    const int row0 = gb * 64 + w * 16;

    int arow = row0 + lm;
    if (arow >= N_NODES) arow = N_NODES - 1;     // clamp (masked on store)
    bf16x8 a[4];
    #pragma unroll
    for (int ki = 0; ki < 4; ++ki) {
        const float* ap = &X[arow * CH + ki * 32 + lk * 8];
        float4 f0 = *(const float4*)ap;
        float4 f1 = *(const float4*)(ap + 4);
        bf16x8 af;
        af[0] = (short)f2bf(f0.x); af[1] = (short)f2bf(f0.y);
        af[2] = (short)f2bf(f0.z); af[3] = (short)f2bf(f0.w);
        af[4] = (short)f2bf(f1.x); af[5] = (short)f2bf(f1.y);
        af[6] = (short)f2bf(f1.z); af[7] = (short)f2bf(f1.w);
        a[ki] = af;
    }

    #pragma unroll
    for (int ct = 0; ct < 8; ++ct) {
        const unsigned short* wp = &Wt1[(ct * 16 + lm) * CH + lk * 8];
        f32x4 acc = {0.f, 0.f, 0.f, 0.f};
        #pragma unroll
        for (int ki = 0; ki < 4; ++ki) {
            bf16x8 bfrag = *(const bf16x8*)&wp[ki * 32];
            acc = __builtin_amdgcn_mfma_f32_16x16x32_bf16(a[ki], bfrag, acc, 0, 0, 0);
        }
        #pragma unroll
        for (int r = 0; r < 4; ++r) {
            int row = row0 + lk * 4 + r;
            if (row < N_NODES)
                HS1u[row * CH + ct * 16 + lm] = f2bf(acc[r]);
        }
    }
}

// ---------------- column scan: per bucket k, exclusive-scan counts over the 250 blocks ----------------
__global__ __launch_bounds__(256) void k_colscan(int* __restrict__ blk_base,
                                                 int* __restrict__ bucket_cnt) {
    __shared__ int sm[256];
    const int tid = threadIdx.x, k = blockIdx.x;
    int v = (tid < B_BIN) ? blk_base[tid * NBUCK + k] : 0;
    sm[tid] = v;
    __syncthreads();
    #pragma unroll
    for (int off = 1; off < 256; off <<= 1) {
        int t = (tid >= off) ? sm[tid - off] : 0;
        __syncthreads();
        sm[tid] += t;
        __syncthreads();
    }
    if (tid < B_BIN) blk_base[tid * NBUCK + k] = sm[tid] - v;   // exclusive
    if (tid == 255) bucket_cnt[k] = sm[255];
}

// ---------------- place packed edges into bucket-contiguous ebuf (internal bucket scan) ----------------
__global__ __launch_bounds__(256) void k_bin_place(const int* __restrict__ ei,
                                                   const int* __restrict__ bucket_cnt,
                                                   const int* __restrict__ blk_base,
                                                   unsigned int* __restrict__ ebuf) {
    __shared__ int sm[256];
    __shared__ int bbase[NBUCK];
    __shared__ int h[NBUCK];
    const int tid = threadIdx.x, b = blockIdx.x;

    int v = (tid < NBUCK) ? bucket_cnt[tid] : 0;
    sm[tid] = v;
    __syncthreads();
    #pragma unroll
    for (int off = 1; off < 256; off <<= 1) {
        int t = (tid >= off) ? sm[tid - off] : 0;
        __syncthreads();
        sm[tid] += t;
        __syncthreads();
    }
    if (tid < NBUCK) bbase[tid] = sm[tid] - v;   // exclusive bucket base
    for (int i = tid; i < NBUCK; i += 256) h[i] = 0;
    __syncthreads();

    const int e0 = b * CHUNK;
    for (int i = tid; i < CHUNK; i += 256) {
        int s = ei[e0 + i];
        int d = ei[N_EDGES + e0 + i];
        int k = d >> 8;
        int loc = atomicAdd(&h[k], 1);
        int pos = bbase[k] + blk_base[b * NBUCK + k] + loc;
        ebuf[pos] = ((unsigned int)s << 8) | (unsigned int)(d & 255);
    }
}

// ---------------- per-bucket exact CSR (rowptr, col, dinv) + in-place scale of HS1u ----------------
__global__ __launch_bounds__(256) void k_bucket_csr(const unsigned int* __restrict__ ebuf,
                                                    const int* __restrict__ bucket_cnt,
                                                    int* __restrict__ rowptr,
                                                    int* __restrict__ col,
                                                    float* __restrict__ dinv,
                                                    unsigned short* __restrict__ HS1u) {
    __shared__ int cnts[256];
    __shared__ int fillc[256];
    __shared__ int sm[256];
    __shared__ float sdinv[256];
    __shared__ int e0s;
    const int tid = threadIdx.x, k = blockIdx.x;
    const int node0 = k << 8;

    int vb = (tid < NBUCK) ? bucket_cnt[tid] : 0;
    sm[tid] = vb;
    __syncthreads();
    #pragma unroll
    for (int off = 1; off < 256; off <<= 1) {
        int t = (tid >= off) ? sm[tid - off] : 0;
        __syncthreads();
        sm[tid] += t;
        __syncthreads();
    }
    if (tid == k) e0s = sm[tid] - vb;
    cnts[tid] = 0;
    __syncthreads();
    const int e0 = e0s;
    const int cnt = bucket_cnt[k];

    for (int i = tid; i < cnt; i += 256)
        atomicAdd(&cnts[ebuf[e0 + i] & 255], 1);
    __syncthreads();

    int v = cnts[tid];
    sm[tid] = v;
    __syncthreads();
    #pragma unroll
    for (int off = 1; off < 256; off <<= 1) {
        int t = (tid >= off) ? sm[tid - off] : 0;
        __syncthreads();
        sm[tid] += t;
        __syncthreads();
    }
    int rp = sm[tid] - v;              // exclusive prefix within bucket
    fillc[tid] = rp;
    float dval = rsqrtf((float)(v + 1));   // +1 self loop
    sdinv[tid] = dval;
    int node = node0 + tid;
    if (node < N_NODES) {
        rowptr[node] = e0 + rp;
        dinv[node] = dval;
    }
    if (k == NBUCK - 1 && tid == 0) rowptr[N_NODES] = N_EDGES;
    __syncthreads();

    for (int i = tid; i < cnt; i += 256) {
        unsigned int pv = ebuf[e0 + i];
        int j = pv & 255;
        int loc = atomicAdd(&fillc[j], 1);
        col[e0 + loc] = (int)(pv >> 8);
    }

    // ---- in-place scale: HS1u[row] *= dinv[row] for this bucket's 256 rows ----
    // (sdinv written before the placement-phase sync; coalesced ushort4 traffic)
    ushort4* H4 = (ushort4*)HS1u;
    #pragma unroll 4
    for (int t = 0; t < 32; ++t) {
        int u = t * 256 + tid;         // 8192 ushort4 units = 256 rows x 32
        int r = u >> 5, c = u & 31;
        int nd = node0 + r;
        if (nd < N_NODES) {
            ushort4 v4 = H4[nd * 32 + c];
            float sc = sdinv[r];
            v4.x = f2bf(bf2f(v4.x) * sc);
            v4.y = f2bf(bf2f(v4.y) * sc);
            v4.z = f2bf(bf2f(v4.z) * sc);
            v4.w = f2bf(bf2f(v4.w) * sc);
            H4[nd * 32 + c] = v4;
        }
    }
}

// ---------------- fused: aggregate layer-1 (prescaled HS1) -> LDS -> GEMM x W2 -> HS2 ----------------
// 64 nodes/block. Phase 1: h1 = relu(dinv[d]*(HS1[d] + sum HS1[s]) + b1) -> bf16 LDS [64][136].
// Phase 2: HS2 = bf16((h1 @ W2) * dinv[row]).
__global__ __launch_bounds__(256) void k_agg_gemm(
        const int* __restrict__ rowptr, const int* __restrict__ col,
        const unsigned short* __restrict__ HS1, const float* __restrict__ dinv,
        const float* __restrict__ b1, const unsigned short* __restrict__ Wt2,
        unsigned short* __restrict__ HS2) {
    __shared__ __align__(16) unsigned short hl[64 * 136];
    const int tid = threadIdx.x;
    const int node0 = blockIdx.x * 64;
    const int lane = tid & 31;
    const ushort4* H4 = (const ushort4*)HS1;

    float4 bb = *(const float4*)&b1[lane * 4];

    #pragma unroll 2
    for (int pass = 0; pass < 8; ++pass) {
        int nl = pass * 8 + (tid >> 5);
        int node = node0 + nl;
        if (node < N_NODES) {
            int e0 = rowptr[node];
            int e1 = rowptr[node + 1];
            float dd = dinv[node];

            ushort4 hv = H4[node * 32 + lane];
            float ax = bf2f(hv.x), ay = bf2f(hv.y), az = bf2f(hv.z), aw = bf2f(hv.w);

            int e = e0;
            for (; e + 3 < e1; e += 4) {
                int s0 = col[e], s1 = col[e + 1], s2 = col[e + 2], s3 = col[e + 3];
                ushort4 v0 = H4[s0 * 32 + lane];
                ushort4 v1 = H4[s1 * 32 + lane];
                ushort4 v2 = H4[s2 * 32 + lane];
                ushort4 v3 = H4[s3 * 32 + lane];
                ax += (bf2f(v0.x) + bf2f(v1.x)) + (bf2f(v2.x) + bf2f(v3.x));
                ay += (bf2f(v0.y) + bf2f(v1.y)) + (bf2f(v2.y) + bf2f(v3.y));
                az += (bf2f(v0.z) + bf2f(v1.z)) + (bf2f(v2.z) + bf2f(v3.z));
                aw += (bf2f(v0.w) + bf2f(v1.w)) + (bf2f(v2.w) + bf2f(v3.w));
            }
            for (; e < e1; ++e) {
                ushort4 va = H4[col[e] * 32 + lane];
                ax += bf2f(va.x); ay += bf2f(va.y); az += bf2f(va.z); aw += bf2f(va.w);
            }

            ushort4 o;
            o.x = f2bf(fmaxf(ax * dd + bb.x, 0.f));
            o.y = f2bf(fmaxf(ay * dd + bb.y, 0.f));
            o.z = f2bf(fmaxf(az * dd + bb.z, 0.f));
            o.w = f2bf(fmaxf(aw * dd + bb.w, 0.f));
            *(ushort4*)&hl[nl * 136 + lane * 4] = o;
        }
    }
    __syncthreads();

    // ---- phase 2: GEMM from LDS ----
    const int l = tid & 63, w = tid >> 6;
    const int lm = l & 15, lk = l >> 4;
    const int row0 = node0 + w * 16;

    bf16x8 a[4];
    #pragma unroll
    for (int ki = 0; ki < 4; ++ki)
        a[ki] = *(const bf16x8*)&hl[(w * 16 + lm) * 136 + ki * 32 + lk * 8];

    #pragma unroll
    for (int ct = 0; ct < 8; ++ct) {
        const unsigned short* wp = &Wt2[(ct * 16 + lm) * CH + lk * 8];
        f32x4 acc = {0.f, 0.f, 0.f, 0.f};
        #pragma unroll
        for (int ki = 0; ki < 4; ++ki) {
            bf16x8 bfrag = *(const bf16x8*)&wp[ki * 32];
            acc = __builtin_amdgcn_mfma_f32_16x16x32_bf16(a[ki], bfrag, acc, 0, 0, 0);
        }
        #pragma unroll
        for (int r = 0; r < 4; ++r) {
            int row = row0 + lk * 4 + r;
            if (row < N_NODES)
                HS2[row * CH + ct * 16 + lm] = f2bf(acc[r] * dinv[row]);
        }
    }
}

// ---------------- final aggregate: out(f32) = relu(dinv*(HS2[self] + sum HS2[col]) + b2) ----------------
__global__ __launch_bounds__(256) void k_agg_final(
        const int* __restrict__ rowptr, const int* __restrict__ col,
        const unsigned short* __restrict__ HS, const float* __restrict__ dinv,
        const float* __restrict__ b, float* __restrict__ OUT) {
    int gid = blockIdx.x * 256 + threadIdx.x;
    int node = gid >> 5;
    if (node >= N_NODES) return;
    int lane = gid & 31;
    const ushort4* H4 = (const ushort4*)HS;

    int e0 = rowptr[node];
    int e1 = rowptr[node + 1];

    ushort4 hself = H4[node * 32 + lane];
    float ax = bf2f(hself.x), ay = bf2f(hself.y), az = bf2f(hself.z), aw = bf2f(hself.w);

    int e = e0;
    for (; e + 3 < e1; e += 4) {
        int s0 = col[e], s1 = col[e + 1], s2 = col[e + 2], s3 = col[e + 3];
        ushort4 v0 = H4[s0 * 32 + lane];
        ushort4 v1 = H4[s1 * 32 + lane];
        ushort4 v2 = H4[s2 * 32 + lane];
        ushort4 v3 = H4[s3 * 32 + lane];
        ax += (bf2f(v0.x) + bf2f(v1.x)) + (bf2f(v2.x) + bf2f(v3.x));
        ay += (bf2f(v0.y) + bf2f(v1.y)) + (bf2f(v2.y) + bf2f(v3.y));
        az += (bf2f(v0.z) + bf2f(v1.z)) + (bf2f(v2.z) + bf2f(v3.z));
        aw += (bf2f(v0.w) + bf2f(v1.w)) + (bf2f(v2.w) + bf2f(v3.w));
    }
    for (; e < e1; ++e) {
        ushort4 va = H4[col[e] * 32 + lane];
        ax += bf2f(va.x); ay += bf2f(va.y); az += bf2f(va.z); aw += bf2f(va.w);
    }

    float di = dinv[node];
    float4 bb = *(const float4*)&b[lane * 4];
    float4 o;
    o.x = fmaxf(ax * di + bb.x, 0.f);
    o.y = fmaxf(ay * di + bb.y, 0.f);
    o.z = fmaxf(az * di + bb.z, 0.f);
    o.w = fmaxf(aw * di + bb.w, 0.f);
    *(float4*)&OUT[node * CH + lane * 4] = o;
}

extern "C" void kernel_launch(void* const* d_in, const int* in_sizes, int n_in,
                              void* d_out, int out_size, void* d_ws, size_t ws_size,
                              hipStream_t stream) {
    const float* x  = (const float*)d_in[0];
    const int*   ei = (const int*)d_in[1];
    const float* W1 = (const float*)d_in[2];
    const float* b1 = (const float*)d_in[3];
    const float* W2 = (const float*)d_in[4];
    const float* b2 = (const float*)d_in[5];
    float* out = (float*)d_out;

    // workspace layout (4B units):
    int* blk_base    = (int*)d_ws;               // 250*196 = 49000 -> pad 49152
    int* bucket_cnt  = blk_base + 49152;         // 256
    int* rowptr      = bucket_cnt + 256;         // 50001 -> pad 50176
    int* col         = rowptr + 50176;           // 800000 -> pad 800256
    float* dinv      = (float*)(col + 800256);   // 50000 -> pad 50176
    unsigned int* ebuf = (unsigned int*)(dinv + 50176);       // 800000 -> pad 800256
    unsigned short* hs1 = (unsigned short*)(ebuf + 800256);   // 6.4M bf16
    unsigned short* hs2  = hs1 + 6400000;                     // 6.4M bf16
    unsigned short* wt1  = hs2 + 6400000;                     // 16384 bf16
    unsigned short* wt2  = wt1 + 16384;                       // 16384 bf16

    const int gA = (N_NODES * 32 + 255) / 256;       // 6250

    k_wt<<<2, 256, 0, stream>>>(W1, W2, wt1, wt2);
    k_mega<<<B_BIN + G_GEMM, 256, 0, stream>>>(ei, blk_base, x, wt1, hs1);
    k_colscan<<<NBUCK, 256, 0, stream>>>(blk_base, bucket_cnt);
    k_bin_place<<<B_BIN, 256, 0, stream>>>(ei, bucket_cnt, blk_base, ebuf);
    k_bucket_csr<<<NBUCK, 256, 0, stream>>>(ebuf, bucket_cnt, rowptr, col, dinv, hs1);
    k_agg_gemm<<<G_GEMM, 256, 0, stream>>>(rowptr, col, hs1, dinv, b1, wt2, hs2);
    k_agg_final<<<gA, 256, 0, stream>>>(rowptr, col, hs2, dinv, b2, out);
}

// Round 9
// 152.606 us; speedup vs baseline: 1.1063x; 1.1063x over previous
//
#include <hip/hip_runtime.h>

#define N_NODES 50000
#define N_EDGES 800000
#define CH 128
#define NBUCK 196          // ceil(50000/256): buckets of 256 dst nodes
#define B_BIN 250          // bin-pass blocks
#define CHUNK 3200         // edges per bin-pass block (250*3200 = 800000)
#define G_GEMM 782         // ceil(50000/64)

typedef __attribute__((ext_vector_type(8))) short bf16x8;
typedef __attribute__((ext_vector_type(8))) unsigned short u16x8;
typedef __attribute__((ext_vector_type(4))) float f32x4;

__device__ __forceinline__ float bf2f(unsigned short u) {
    union { unsigned int i; float f; } c;
    c.i = ((unsigned int)u) << 16;
    return c.f;
}
__device__ __forceinline__ unsigned short f2bf(float f) {
    union { float f; unsigned int i; } c;
    c.f = f;
    unsigned int lsb = (c.i >> 16) & 1u;
    c.i += 0x7fffu + lsb;          // round-to-nearest-even
    return (unsigned short)(c.i >> 16);
}

// ---------------- W transpose to bf16: Wt[n][k] = bf16(W[k][n]); 2 blocks ----------------
__global__ __launch_bounds__(256) void k_wt(const float* __restrict__ Wa,
                                            const float* __restrict__ Wb,
                                            unsigned short* __restrict__ Wta,
                                            unsigned short* __restrict__ Wtb) {
    const float* W = blockIdx.x ? Wb : Wa;
    unsigned short* Wt = blockIdx.x ? Wtb : Wta;
    const int tid = threadIdx.x;
    for (int i = 0; i < 64; ++i) {
        int idx = i * 256 + tid;           // n*128 + k
        int n = idx >> 7, kk = idx & 127;
        Wt[idx] = f2bf(W[kk * CH + n]);
    }
}

// ---------------- mega: blocks [0,B_BIN) = bucket histogram; rest = GEMM1 (unscaled) ----------------
// GEMM1: HS1u = bf16(X @ W1). X read f32, converted inline. 4 waves/block, 16 rows/wave.
// C/D layout (HW-verified): col = l&15, row = (l>>4)*4 + reg.
__global__ __launch_bounds__(256) void k_mega(
        const int* __restrict__ ei, int* __restrict__ blk_base,
        const float* __restrict__ X, const unsigned short* __restrict__ Wt1,
        unsigned short* __restrict__ HS1u) {
    const int tid = threadIdx.x;
    const int b = blockIdx.x;

    if (b < B_BIN) {       // ---- bucket histogram ----
        __shared__ int h[NBUCK];
        for (int i = tid; i < NBUCK; i += 256) h[i] = 0;
        __syncthreads();
        const int e0 = b * CHUNK;
        const int* dst = ei + N_EDGES;
        for (int i = tid; i < CHUNK; i += 256)
            atomicAdd(&h[dst[e0 + i] >> 8], 1);
        __syncthreads();
        for (int k = tid; k < NBUCK; k += 256)
            blk_base[b * NBUCK + k] = h[k];
        return;
    }

    // ---- GEMM1 ----
    const int gb = b - B_BIN;
    const int l = tid & 63, w = tid >> 6;
    const int lm = l & 15, lk = l >> 4;
    const int row0 = gb * 64 + w * 16;

    int arow = row0 + lm;
    if (arow >= N_NODES) arow = N_NODES - 1;     // clamp (masked on store)
    bf16x8 a[4];
    #pragma unroll
    for (int ki = 0; ki < 4; ++ki) {
        const float* ap = &X[arow * CH + ki * 32 + lk * 8];
        float4 f0 = *(const float4*)ap;
        float4 f1 = *(const float4*)(ap + 4);
        bf16x8 af;
        af[0] = (short)f2bf(f0.x); af[1] = (short)f2bf(f0.y);
        af[2] = (short)f2bf(f0.z); af[3] = (short)f2bf(f0.w);
        af[4] = (short)f2bf(f1.x); af[5] = (short)f2bf(f1.y);
        af[6] = (short)f2bf(f1.z); af[7] = (short)f2bf(f1.w);
        a[ki] = af;
    }

    #pragma unroll
    for (int ct = 0; ct < 8; ++ct) {
        const unsigned short* wp = &Wt1[(ct * 16 + lm) * CH + lk * 8];
        f32x4 acc = {0.f, 0.f, 0.f, 0.f};
        #pragma unroll
        for (int ki = 0; ki < 4; ++ki) {
            bf16x8 bfrag = *(const bf16x8*)&wp[ki * 32];
            acc = __builtin_amdgcn_mfma_f32_16x16x32_bf16(a[ki], bfrag, acc, 0, 0, 0);
        }
        #pragma unroll
        for (int r = 0; r < 4; ++r) {
            int row = row0 + lk * 4 + r;
            if (row < N_NODES)
                HS1u[row * CH + ct * 16 + lm] = f2bf(acc[r]);
        }
    }
}

// ---------------- column scan: per bucket k, exclusive-scan counts over the 250 blocks ----------------
__global__ __launch_bounds__(256) void k_colscan(int* __restrict__ blk_base,
                                                 int* __restrict__ bucket_cnt) {
    __shared__ int sm[256];
    const int tid = threadIdx.x, k = blockIdx.x;
    int v = (tid < B_BIN) ? blk_base[tid * NBUCK + k] : 0;
    sm[tid] = v;
    __syncthreads();
    #pragma unroll
    for (int off = 1; off < 256; off <<= 1) {
        int t = (tid >= off) ? sm[tid - off] : 0;
        __syncthreads();
        sm[tid] += t;
        __syncthreads();
    }
    if (tid < B_BIN) blk_base[tid * NBUCK + k] = sm[tid] - v;   // exclusive
    if (tid == 255) bucket_cnt[k] = sm[255];
}

// ---------------- place packed edges into bucket-contiguous ebuf (internal bucket scan) ----------------
__global__ __launch_bounds__(256) void k_bin_place(const int* __restrict__ ei,
                                                   const int* __restrict__ bucket_cnt,
                                                   const int* __restrict__ blk_base,
                                                   unsigned int* __restrict__ ebuf) {
    __shared__ int sm[256];
    __shared__ int bbase[NBUCK];
    __shared__ int h[NBUCK];
    const int tid = threadIdx.x, b = blockIdx.x;

    int v = (tid < NBUCK) ? bucket_cnt[tid] : 0;
    sm[tid] = v;
    __syncthreads();
    #pragma unroll
    for (int off = 1; off < 256; off <<= 1) {
        int t = (tid >= off) ? sm[tid - off] : 0;
        __syncthreads();
        sm[tid] += t;
        __syncthreads();
    }
    if (tid < NBUCK) bbase[tid] = sm[tid] - v;   // exclusive bucket base
    for (int i = tid; i < NBUCK; i += 256) h[i] = 0;
    __syncthreads();

    const int e0 = b * CHUNK;
    for (int i = tid; i < CHUNK; i += 256) {
        int s = ei[e0 + i];
        int d = ei[N_EDGES + e0 + i];
        int k = d >> 8;
        int loc = atomicAdd(&h[k], 1);
        int pos = bbase[k] + blk_base[b * NBUCK + k] + loc;
        ebuf[pos] = ((unsigned int)s << 8) | (unsigned int)(d & 255);
    }
}

// ---------------- per-bucket exact CSR (rowptr, col, dinv) + in-place scale of HS1u ----------------
__global__ __launch_bounds__(256) void k_bucket_csr(const unsigned int* __restrict__ ebuf,
                                                    const int* __restrict__ bucket_cnt,
                                                    int* __restrict__ rowptr,
                                                    int* __restrict__ col,
                                                    float* __restrict__ dinv,
                                                    unsigned short* __restrict__ HS1u) {
    __shared__ int cnts[256];
    __shared__ int fillc[256];
    __shared__ int sm[256];
    __shared__ float sdinv[256];
    __shared__ int e0s;
    const int tid = threadIdx.x, k = blockIdx.x;
    const int node0 = k << 8;

    int vb = (tid < NBUCK) ? bucket_cnt[tid] : 0;
    sm[tid] = vb;
    __syncthreads();
    #pragma unroll
    for (int off = 1; off < 256; off <<= 1) {
        int t = (tid >= off) ? sm[tid - off] : 0;
        __syncthreads();
        sm[tid] += t;
        __syncthreads();
    }
    if (tid == k) e0s = sm[tid] - vb;
    cnts[tid] = 0;
    __syncthreads();
    const int e0 = e0s;
    const int cnt = bucket_cnt[k];

    for (int i = tid; i < cnt; i += 256)
        atomicAdd(&cnts[ebuf[e0 + i] & 255], 1);
    __syncthreads();

    int v = cnts[tid];
    sm[tid] = v;
    __syncthreads();
    #pragma unroll
    for (int off = 1; off < 256; off <<= 1) {
        int t = (tid >= off) ? sm[tid - off] : 0;
        __syncthreads();
        sm[tid] += t;
        __syncthreads();
    }
    int rp = sm[tid] - v;              // exclusive prefix within bucket
    fillc[tid] = rp;
    float dval = rsqrtf((float)(v + 1));   // +1 self loop
    sdinv[tid] = dval;
    int node = node0 + tid;
    if (node < N_NODES) {
        rowptr[node] = e0 + rp;
        dinv[node] = dval;
    }
    if (k == NBUCK - 1 && tid == 0) rowptr[N_NODES] = N_EDGES;
    __syncthreads();

    for (int i = tid; i < cnt; i += 256) {
        unsigned int pv = ebuf[e0 + i];
        int j = pv & 255;
        int loc = atomicAdd(&fillc[j], 1);
        col[e0 + loc] = (int)(pv >> 8);
    }

    // ---- in-place scale: HS1[row] = HS1u[row] * dinv[row] for this bucket's 256 rows ----
    ushort4* H4 = (ushort4*)HS1u;
    #pragma unroll 4
    for (int t = 0; t < 32; ++t) {
        int u = t * 256 + tid;         // 8192 ushort4 units = 256 rows x 32
        int r = u >> 5, c = u & 31;
        int nd = node0 + r;
        if (nd < N_NODES) {
            ushort4 v4 = H4[nd * 32 + c];
            float sc = sdinv[r];
            v4.x = f2bf(bf2f(v4.x) * sc);
            v4.y = f2bf(bf2f(v4.y) * sc);
            v4.z = f2bf(bf2f(v4.z) * sc);
            v4.w = f2bf(bf2f(v4.w) * sc);
            H4[nd * 32 + c] = v4;
        }
    }
}

// ---------------- aggregate: 16 lanes/node, ushort8 per lane (16B), f32 accumulate ----------------
// MODE 0 (layer 1): OUT = bf16( dinv * relu(dinv*(H[self]+Sum H[col]) + b) )   [pre-scaled for next gather]
// MODE 1 (layer 2): OUT = bf16( dinv*(H[self]+Sum H[col]) )                     [feeds final GEMM]
template <int MODE>
__global__ __launch_bounds__(256) void k_agg(
        const int* __restrict__ rowptr, const int* __restrict__ col,
        const unsigned short* __restrict__ H, const float* __restrict__ dinv,
        const float* __restrict__ b, unsigned short* __restrict__ OUT) {
    int gid = blockIdx.x * 256 + threadIdx.x;   // 3125 blocks * 256 = 800000 exactly
    int node = gid >> 4;
    if (node >= N_NODES) return;
    int lane = gid & 15;
    const u16x8* H8 = (const u16x8*)H;          // 16 u16x8 per 128-ch row

    int e0 = rowptr[node];
    int e1 = rowptr[node + 1];

    u16x8 hv = H8[node * 16 + lane];
    float acc[8];
    #pragma unroll
    for (int j = 0; j < 8; ++j) acc[j] = bf2f(hv[j]);

    int e = e0;
    for (; e + 3 < e1; e += 4) {
        int s0 = col[e], s1 = col[e + 1], s2 = col[e + 2], s3 = col[e + 3];
        u16x8 v0 = H8[s0 * 16 + lane];
        u16x8 v1 = H8[s1 * 16 + lane];
        u16x8 v2 = H8[s2 * 16 + lane];
        u16x8 v3 = H8[s3 * 16 + lane];
        #pragma unroll
        for (int j = 0; j < 8; ++j)
            acc[j] += (bf2f(v0[j]) + bf2f(v1[j])) + (bf2f(v2[j]) + bf2f(v3[j]));
    }
    for (; e < e1; ++e) {
        u16x8 v = H8[col[e] * 16 + lane];
        #pragma unroll
        for (int j = 0; j < 8; ++j) acc[j] += bf2f(v[j]);
    }

    float di = dinv[node];
    u16x8 o;
    if (MODE == 0) {
        float4 b0 = *(const float4*)&b[lane * 8];
        float4 b1v = *(const float4*)&b[lane * 8 + 4];
        float bb[8] = {b0.x, b0.y, b0.z, b0.w, b1v.x, b1v.y, b1v.z, b1v.w};
        #pragma unroll
        for (int j = 0; j < 8; ++j)
            o[j] = f2bf(fmaxf(acc[j] * di + bb[j], 0.f) * di);
    } else {
        #pragma unroll
        for (int j = 0; j < 8; ++j)
            o[j] = f2bf(acc[j] * di);
    }
    *(u16x8*)&OUT[node * CH + lane * 8] = o;
}

// ---------------- final GEMM: OUT(f32) = relu(A2 @ W2 + b2) ----------------
__global__ __launch_bounds__(256) void k_gemm_out(
        const unsigned short* __restrict__ A2,   // [N][128] bf16 (= Ahat h1, fully scaled)
        const unsigned short* __restrict__ Wt2,  // [128][128] bf16, n-major
        const float* __restrict__ b2,
        float* __restrict__ OUT) {
    const int tid = threadIdx.x;
    const int l = tid & 63, w = tid >> 6;
    const int lm = l & 15, lk = l >> 4;
    const int row0 = blockIdx.x * 64 + w * 16;

    int arow = row0 + lm;
    if (arow >= N_NODES) arow = N_NODES - 1;     // clamp (masked on store)
    bf16x8 a[4];
    #pragma unroll
    for (int ki = 0; ki < 4; ++ki)
        a[ki] = *(const bf16x8*)&A2[arow * CH + ki * 32 + lk * 8];

    #pragma unroll
    for (int ct = 0; ct < 8; ++ct) {
        const unsigned short* wp = &Wt2[(ct * 16 + lm) * CH + lk * 8];
        f32x4 acc = {0.f, 0.f, 0.f, 0.f};
        #pragma unroll
        for (int ki = 0; ki < 4; ++ki) {
            bf16x8 bfrag = *(const bf16x8*)&wp[ki * 32];
            acc = __builtin_amdgcn_mfma_f32_16x16x32_bf16(a[ki], bfrag, acc, 0, 0, 0);
        }
        float bb = b2[ct * 16 + lm];
        #pragma unroll
        for (int r = 0; r < 4; ++r) {
            int row = row0 + lk * 4 + r;
            if (row < N_NODES)
                OUT[row * CH + ct * 16 + lm] = fmaxf(acc[r] + bb, 0.f);
        }
    }
}

extern "C" void kernel_launch(void* const* d_in, const int* in_sizes, int n_in,
                              void* d_out, int out_size, void* d_ws, size_t ws_size,
                              hipStream_t stream) {
    const float* x  = (const float*)d_in[0];
    const int*   ei = (const int*)d_in[1];
    const float* W1 = (const float*)d_in[2];
    const float* b1 = (const float*)d_in[3];
    const float* W2 = (const float*)d_in[4];
    const float* b2 = (const float*)d_in[5];
    float* out = (float*)d_out;

    // workspace layout (4B units):
    int* blk_base    = (int*)d_ws;               // 250*196 = 49000 -> pad 49152
    int* bucket_cnt  = blk_base + 49152;         // 256
    int* rowptr      = bucket_cnt + 256;         // 50001 -> pad 50176
    int* col         = rowptr + 50176;           // 800000 -> pad 800256
    float* dinv      = (float*)(col + 800256);   // 50000 -> pad 50176
    unsigned int* ebuf = (unsigned int*)(dinv + 50176);       // 800000 -> pad 800256
    unsigned short* hs1 = (unsigned short*)(ebuf + 800256);   // 6.4M bf16
    unsigned short* h1p = hs1 + 6400000;                      // 6.4M bf16
    unsigned short* a2  = h1p + 6400000;                      // 6.4M bf16
    unsigned short* wt1 = a2 + 6400000;                       // 16384 bf16
    unsigned short* wt2 = wt1 + 16384;                        // 16384 bf16

    const int gAgg = 3125;      // 50000 nodes * 16 lanes / 256

    k_wt<<<2, 256, 0, stream>>>(W1, W2, wt1, wt2);
    k_mega<<<B_BIN + G_GEMM, 256, 0, stream>>>(ei, blk_base, x, wt1, hs1);
    k_colscan<<<NBUCK, 256, 0, stream>>>(blk_base, bucket_cnt);
    k_bin_place<<<B_BIN, 256, 0, stream>>>(ei, bucket_cnt, blk_base, ebuf);
    k_bucket_csr<<<NBUCK, 256, 0, stream>>>(ebuf, bucket_cnt, rowptr, col, dinv, hs1);
    k_agg<0><<<gAgg, 256, 0, stream>>>(rowptr, col, hs1, dinv, b1, h1p);   // h1p = dinv*relu(...)
    k_agg<1><<<gAgg, 256, 0, stream>>>(rowptr, col, h1p, dinv, nullptr, a2); // a2 = Ahat h1
    k_gemm_out<<<G_GEMM, 256, 0, stream>>>(a2, wt2, b2, out);
}